// Round 17
// baseline (80.283 us; speedup 1.0000x reference)
//
#include <hip/hip_runtime.h>
#include <hip/hip_bf16.h>
// R17: packed bf16 conversion (__float22bfloat162_rn -> v_cvt_pk_bf16_f32) in all
// MFMA staging (k1/k2/k7); k6 merged into k7 (per-block bm/bs reduction). k3 as R15.

#define NEGINF (-1e30f)

typedef __attribute__((ext_vector_type(8))) short short8;
typedef __attribute__((ext_vector_type(4))) float f32x4;
union S8 { short8 s; unsigned u[4]; };

__device__ inline float waveRedSum(float v){
  #pragma unroll
  for (int o = 32; o > 0; o >>= 1) v += __shfl_down(v, o, 64);
  return v;
}
__device__ inline float waveRedMax(float v){
  #pragma unroll
  for (int o = 32; o > 0; o >>= 1) v = fmaxf(v, __shfl_down(v, o, 64));
  return v;
}
__device__ inline float4 f4z(){ return make_float4(0.f,0.f,0.f,0.f); }
#define F4C(v, c) ((c)==0?(v).x:(c)==1?(v).y:(c)==2?(v).z:(v).w)

__device__ inline unsigned pack2bf(float f0, float f1){
  __hip_bfloat162 h2 = __float22bfloat162_rn(make_float2(f0, f1));
  unsigned u; __builtin_memcpy(&u, &h2, 4); return u;
}
// split (f0,f1) into packed hi word and packed lo word (hi RNE, lo = residual RNE)
__device__ inline void split2(float f0, float f1, unsigned &hi, unsigned &lo){
  hi = pack2bf(f0, f1);
  lo = pack2bf(f0 - __uint_as_float(hi << 16),
               f1 - __uint_as_float(hi & 0xffff0000u));
}

// ================= K1: H = feat @ W^T + Wb  [4096 x 300], K=768, MFMA ==============
__global__ __launch_bounds__(256) void k1_h(const float* __restrict__ A,
                                            const float* __restrict__ W,
                                            const float* __restrict__ Wb,
                                            float* __restrict__ H){
  __shared__ short Ah[2][64*40];
  __shared__ short Al[2][64*40];
  __shared__ short Bh[2][64*40];
  __shared__ short Bl[2][64*40];
  const int fid = blockIdx.x;
  const int wl  = (fid & 7) * 40 + (fid >> 3);
  const int y = wl / 5, x = wl % 5;
  const int m0 = y * 64, c0 = x * 64;
  const int t = threadIdx.x;
  const int lane = t & 63, w = t >> 6;
  const int wr = w >> 1, wc = w & 1;
  const int srow = t >> 2, kq = (t & 3) * 8;
  const bool bok = (c0 + srow) < 300;
  const float* Arow = A + (size_t)(m0 + srow) * 768 + kq;
  const float* Wrow = W + (size_t)(c0 + srow) * 768 + kq;
  float4 ra0, ra1, rb0, rb1;
#define K1_LD(kt) { \
    ra0 = *(const float4*)(Arow + (kt)); \
    ra1 = *(const float4*)(Arow + (kt) + 4); \
    rb0 = bok ? *(const float4*)(Wrow + (kt)) : f4z(); \
    rb1 = bok ? *(const float4*)(Wrow + (kt) + 4) : f4z(); }
  K1_LD(0)
  f32x4 acc[2][2];
  #pragma unroll
  for (int i = 0; i < 2; i++)
    #pragma unroll
    for (int j = 0; j < 2; j++)
      acc[i][j] = (f32x4){0.f, 0.f, 0.f, 0.f};
  const int fr = lane & 15;
  const int fk = (lane >> 4) * 8;
  int p = 0;
  for (int tile = 0; tile < 24; ++tile){
    {
      float av[8] = {ra0.x, ra0.y, ra0.z, ra0.w, ra1.x, ra1.y, ra1.z, ra1.w};
      float bv[8] = {rb0.x, rb0.y, rb0.z, rb0.w, rb1.x, rb1.y, rb1.z, rb1.w};
      S8 vah, val_, vbh, vbl;
      #pragma unroll
      for (int i = 0; i < 4; i++){
        split2(av[2*i], av[2*i+1], vah.u[i], val_.u[i]);
        split2(bv[2*i], bv[2*i+1], vbh.u[i], vbl.u[i]);
      }
      const int o = srow * 40 + kq;
      *(short8*)&Ah[p][o] = vah.s;
      *(short8*)&Al[p][o] = val_.s;
      *(short8*)&Bh[p][o] = vbh.s;
      *(short8*)&Bl[p][o] = vbl.s;
    }
    __syncthreads();
    if (tile < 23) K1_LD((tile + 1) * 32)
    {
      const int a0o = (wr*32      + fr) * 40 + fk;
      const int a1o = (wr*32 + 16 + fr) * 40 + fk;
      const int b0o = (wc*32      + fr) * 40 + fk;
      const int b1o = (wc*32 + 16 + fr) * 40 + fk;
      short8 fAh[2], fAl[2], fBh[2], fBl[2];
      fAh[0] = *(short8*)&Ah[p][a0o]; fAh[1] = *(short8*)&Ah[p][a1o];
      fAl[0] = *(short8*)&Al[p][a0o]; fAl[1] = *(short8*)&Al[p][a1o];
      fBh[0] = *(short8*)&Bh[p][b0o]; fBh[1] = *(short8*)&Bh[p][b1o];
      fBl[0] = *(short8*)&Bl[p][b0o]; fBl[1] = *(short8*)&Bl[p][b1o];
      #pragma unroll
      for (int sm = 0; sm < 2; sm++)
        #pragma unroll
        for (int sn = 0; sn < 2; sn++){
          acc[sm][sn] = __builtin_amdgcn_mfma_f32_16x16x32_bf16(fAh[sm], fBh[sn], acc[sm][sn], 0, 0, 0);
          acc[sm][sn] = __builtin_amdgcn_mfma_f32_16x16x32_bf16(fAh[sm], fBl[sn], acc[sm][sn], 0, 0, 0);
          acc[sm][sn] = __builtin_amdgcn_mfma_f32_16x16x32_bf16(fAl[sm], fBh[sn], acc[sm][sn], 0, 0, 0);
        }
    }
    p ^= 1;
  }
#undef K1_LD
  const int crow = (lane >> 4) * 4;
  const int ccol = lane & 15;
  #pragma unroll
  for (int sn = 0; sn < 2; sn++){
    const int gcol = c0 + wc*32 + sn*16 + ccol;
    if (gcol < 300){
      const float bi = Wb[gcol];
      #pragma unroll
      for (int sm = 0; sm < 2; sm++){
        const int rbase = m0 + wr*32 + sm*16 + crow;
        #pragma unroll
        for (int r = 0; r < 4; r++)
          H[(size_t)(rbase + r) * 300 + gcol] = acc[sm][sn][r] + bi;
      }
    }
  }
}

// ================= K2: S = H @ Bmat^T (+a1b cols<64)  [4096 x 128], K=300, MFMA ====
__global__ __launch_bounds__(256) void k2_s(const float* __restrict__ Hm,
                                            const float* __restrict__ a1w,
                                            const float* __restrict__ a1b,
                                            float* __restrict__ S){
  __shared__ short Ah[2][64*40];
  __shared__ short Al[2][64*40];
  __shared__ short Bh[2][64*40];
  __shared__ short Bl[2][64*40];
  const int fid = blockIdx.x;
  const int wl  = (fid & 7) * 16 + (fid >> 3);
  const int y = wl >> 1, x = wl & 1;
  const int m0 = y * 64, c0 = x * 64;
  const int t = threadIdx.x;
  const int lane = t & 63, w = t >> 6;
  const int wr = w >> 1, wc = w & 1;
  const int srow = t >> 2, kq = (t & 3) * 8;
  const int brow = c0 + srow;
  const float* Arow = Hm + (size_t)(m0 + srow) * 300;
  const float* Brow = (brow < 64) ? (a1w + (size_t)brow * 600)
                                  : (a1w + (size_t)(brow - 64) * 600 + 300);
  float4 ra0, ra1, rb0, rb1;
#define K2_LD(kt) { \
    const int k = (kt) + kq; \
    ra0 = (k <= 296) ? *(const float4*)(Arow + k)     : f4z(); \
    ra1 = (k <= 292) ? *(const float4*)(Arow + k + 4) : f4z(); \
    rb0 = (k <= 296) ? *(const float4*)(Brow + k)     : f4z(); \
    rb1 = (k <= 292) ? *(const float4*)(Brow + k + 4) : f4z(); }
  K2_LD(0)
  f32x4 acc[2][2];
  #pragma unroll
  for (int i = 0; i < 2; i++)
    #pragma unroll
    for (int j = 0; j < 2; j++)
      acc[i][j] = (f32x4){0.f, 0.f, 0.f, 0.f};
  const int fr = lane & 15;
  const int fk = (lane >> 4) * 8;
  int p = 0;
  for (int tile = 0; tile < 10; ++tile){
    {
      float av[8] = {ra0.x, ra0.y, ra0.z, ra0.w, ra1.x, ra1.y, ra1.z, ra1.w};
      float bv[8] = {rb0.x, rb0.y, rb0.z, rb0.w, rb1.x, rb1.y, rb1.z, rb1.w};
      S8 vah, val_, vbh, vbl;
      #pragma unroll
      for (int i = 0; i < 4; i++){
        split2(av[2*i], av[2*i+1], vah.u[i], val_.u[i]);
        split2(bv[2*i], bv[2*i+1], vbh.u[i], vbl.u[i]);
      }
      const int o = srow * 40 + kq;
      *(short8*)&Ah[p][o] = vah.s;
      *(short8*)&Al[p][o] = val_.s;
      *(short8*)&Bh[p][o] = vbh.s;
      *(short8*)&Bl[p][o] = vbl.s;
    }
    __syncthreads();
    if (tile < 9) K2_LD((tile + 1) * 32)
    {
      const int a0o = (wr*32      + fr) * 40 + fk;
      const int a1o = (wr*32 + 16 + fr) * 40 + fk;
      const int b0o = (wc*32      + fr) * 40 + fk;
      const int b1o = (wc*32 + 16 + fr) * 40 + fk;
      short8 fAh[2], fAl[2], fBh[2], fBl[2];
      fAh[0] = *(short8*)&Ah[p][a0o]; fAh[1] = *(short8*)&Ah[p][a1o];
      fAl[0] = *(short8*)&Al[p][a0o]; fAl[1] = *(short8*)&Al[p][a1o];
      fBh[0] = *(short8*)&Bh[p][b0o]; fBh[1] = *(short8*)&Bh[p][b1o];
      fBl[0] = *(short8*)&Bl[p][b0o]; fBl[1] = *(short8*)&Bl[p][b1o];
      #pragma unroll
      for (int sm = 0; sm < 2; sm++)
        #pragma unroll
        for (int sn = 0; sn < 2; sn++){
          acc[sm][sn] = __builtin_amdgcn_mfma_f32_16x16x32_bf16(fAh[sm], fBh[sn], acc[sm][sn], 0, 0, 0);
          acc[sm][sn] = __builtin_amdgcn_mfma_f32_16x16x32_bf16(fAh[sm], fBl[sn], acc[sm][sn], 0, 0, 0);
          acc[sm][sn] = __builtin_amdgcn_mfma_f32_16x16x32_bf16(fAl[sm], fBh[sn], acc[sm][sn], 0, 0, 0);
        }
    }
    p ^= 1;
  }
#undef K2_LD
  const int crow = (lane >> 4) * 4;
  const int ccol = lane & 15;
  #pragma unroll
  for (int sn = 0; sn < 2; sn++){
    const int gcol = c0 + wc*32 + sn*16 + ccol;
    const float bi = (gcol < 64) ? a1b[gcol] : 0.f;
    #pragma unroll
    for (int sm = 0; sm < 2; sm++){
      const int rbase = m0 + wr*32 + sm*16 + crow;
      #pragma unroll
      for (int r = 0; r < 4; r++)
        S[(size_t)(rbase + r) * 128 + gcol] = acc[sm][sn][r] + bi;
    }
  }
}

// ================= K3: logits + mask + per-block (max, sum-exp) =====================
__global__ __launch_bounds__(256) void k3_logits(const float* __restrict__ S,
                                                 const float* __restrict__ adj,
                                                 const float* __restrict__ a2w,
                                                 const float* __restrict__ a2b,
                                                 float* __restrict__ L,
                                                 float* __restrict__ bm,
                                                 float* __restrict__ bs){
  __shared__ float sj_s[64*68];
  __shared__ float w_s[64];
  __shared__ float redm[4];
  __shared__ float reds[4];
  __shared__ float smax;
  const int b  = blockIdx.z;
  const int i0 = blockIdx.y * 32;
  const int j0 = blockIdx.x * 64;
  const int t  = threadIdx.x;
  const int j = t & 63, iq = t >> 6;
  if (t < 16) *(float4*)&w_s[t*4] = *(const float4*)&a2w[t*4];
  #pragma unroll
  for (int q = 0; q < 4; q++){
    int c = t + q*256; int r = c >> 4, c4 = c & 15;
    *(float4*)&sj_s[r*68 + c4*4] = *(const float4*)&S[(size_t)(b*512 + j0 + r)*128 + 64 + c4*4];
  }
  float vsi[8];
  #pragma unroll
  for (int r = 0; r < 8; r++)
    vsi[r] = S[(size_t)(b*512 + i0 + r*4 + iq) * 128 + j];
  __syncthreads();
  const float a2bv = a2b[0];
  float accA[8][4];
  #pragma unroll
  for (int r = 0; r < 8; r++)
    #pragma unroll
    for (int c = 0; c < 4; c++) accA[r][c] = 0.f;
  #pragma unroll
  for (int k4 = 0; k4 < 16; k4++){
    const float4 sj4 = *(const float4*)&sj_s[j*68 + k4*4];
    const float4 w4  = *(const float4*)&w_s[k4*4];
    #pragma unroll
    for (int c = 0; c < 4; c++){
      const int k = k4*4 + c;
      const float sjc = F4C(sj4, c);
      const float wc  = F4C(w4, c);
      #pragma unroll
      for (int r = 0; r < 8; r++){
        const float s = __int_as_float(__builtin_amdgcn_readlane(__float_as_int(vsi[r]), k));
        accA[r][c] += fmaxf(s + sjc, 0.f) * wc;
      }
    }
  }
  float l_arr[8];
  float locmax = -3e38f;
  #pragma unroll
  for (int r = 0; r < 8; r++){
    const int i = r*4 + iq;
    float e = ((accA[r][0] + accA[r][1]) + (accA[r][2] + accA[r][3])) + a2bv;
    e = (e >= 0.f) ? e : 0.01f * e;
    size_t idxg = (size_t)(b*512 + i0 + i)*512 + j0 + j;
    float l = (adj[idxg] != 0.f) ? e : NEGINF;
    l_arr[r] = l;
    L[idxg] = l;
    locmax = fmaxf(locmax, l);
  }
  float m = waveRedMax(locmax);
  if ((t & 63) == 0) redm[t >> 6] = m;
  __syncthreads();
  if (t == 0) smax = fmaxf(fmaxf(redm[0], redm[1]), fmaxf(redm[2], redm[3]));
  __syncthreads();
  const float mb = smax;
  float sacc = 0.f;
  #pragma unroll
  for (int r = 0; r < 8; r++) sacc += __expf(l_arr[r] - mb);
  sacc = waveRedSum(sacc);
  if ((t & 63) == 0) reds[t >> 6] = sacc;
  __syncthreads();
  if (t == 0){
    const int bid = (blockIdx.z * 16 + blockIdx.y) * 8 + blockIdx.x;
    bm[bid] = mb;
    bs[bid] = (reds[0] + reds[1]) + (reds[2] + reds[3]);
  }
}

// ================= K7: out = (exp(L-maxg) @ H) / sums, MFMA; k6 reduction in-block ==
__global__ __launch_bounds__(256) void k7_out(const float* __restrict__ Lr,
                                              const float* __restrict__ Hm,
                                              const float* __restrict__ bm,
                                              const float* __restrict__ bs,
                                              float* __restrict__ out){
  __shared__ short Ah[2][64*40];
  __shared__ short Al[2][64*40];
  __shared__ short Bh[2][64*40];
  __shared__ short Bl[2][64*40];
  __shared__ float rmx[4], rsm[4];
  const int fid = blockIdx.x;
  const int b = fid & 7, idx = fid >> 3;
  const int y = idx / 5, x = idx % 5;
  const int m0 = y * 64, c0 = x * 64;
  const int t = threadIdx.x;
  const int lane = t & 63, wv = t >> 6;
  const int wr = wv >> 1, wc = wv & 1;
  // ---- in-block reduction of (bm, bs) for batch b (replaces k6) ----
  const float mload = (t < 128) ? bm[b*128 + t] : -3e38f;
  float mm = waveRedMax(mload);
  if (lane == 0) rmx[wv] = mm;
  __syncthreads();
  const float mx = fmaxf(fmaxf(rmx[0], rmx[1]), fmaxf(rmx[2], rmx[3]));
  float sload = (t < 128) ? bs[b*128 + t] * __expf(mload - mx) : 0.f;
  float ss = waveRedSum(sload);
  if (lane == 0) rsm[wv] = ss;
  __syncthreads();
  const float invs = 1.0f / ((rsm[0] + rsm[1]) + (rsm[2] + rsm[3]));
  // ---- GEMM ----
  const int srow = t >> 2, kq = (t & 3) * 8;
  const float* Lrow = Lr + (size_t)(b*512 + m0 + srow) * 512 + kq;
  const int tk = t >> 4, tn = t & 15;
  const int k0 = tk * 2, n0 = tn * 4;
  const int gcolB = c0 + n0;
  const bool bok = gcolB < 300;
  float4 ra0, ra1, hb0, hb1;
#define K7_LD(kt) { \
    ra0 = *(const float4*)(Lrow + (kt)); \
    ra1 = *(const float4*)(Lrow + (kt) + 4); \
    const float* hr = Hm + (size_t)(b*512 + (kt) + k0) * 300 + gcolB; \
    hb0 = bok ? *(const float4*)hr : f4z(); \
    hb1 = bok ? *(const float4*)(hr + 300) : f4z(); }
  K7_LD(0)
  f32x4 acc[2][2];
  #pragma unroll
  for (int i = 0; i < 2; i++)
    #pragma unroll
    for (int jj = 0; jj < 2; jj++)
      acc[i][jj] = (f32x4){0.f, 0.f, 0.f, 0.f};
  const int fr = lane & 15;
  const int fg = lane >> 4;
  const int fk = fg * 8;
  int p = 0;
  for (int tile = 0; tile < 16; ++tile){
    {
      float av[8] = {ra0.x, ra0.y, ra0.z, ra0.w, ra1.x, ra1.y, ra1.z, ra1.w};
      S8 vah, val_;
      #pragma unroll
      for (int i = 0; i < 4; i++){
        const float e0 = __expf(av[2*i]   - mx);
        const float e1 = __expf(av[2*i+1] - mx);
        split2(e0, e1, vah.u[i], val_.u[i]);
      }
      const int o = srow * 40 + kq;
      *(short8*)&Ah[p][o] = vah.s;
      *(short8*)&Al[p][o] = val_.s;
      #pragma unroll
      for (int i = 0; i < 4; i++){
        const float v0 = F4C(hb0, i), v1 = F4C(hb1, i);
        unsigned hp, lp;
        split2(v0, v1, hp, lp);
        const int n = n0 + i;
        const int kbs = (k0 >> 3) ^ (n & 3);
        const int soff = n*40 + kbs*8 + (k0 & 7);
        *(unsigned*)&Bh[p][soff] = hp;
        *(unsigned*)&Bl[p][soff] = lp;
      }
    }
    __syncthreads();
    if (tile < 15) K7_LD((tile + 1) * 32)
    {
      const int a0o = (wr*32      + fr) * 40 + fk;
      const int a1o = (wr*32 + 16 + fr) * 40 + fk;
      const int nb0 = wc*32      + fr;
      const int nb1 = wc*32 + 16 + fr;
      const int b0o = nb0*40 + (fg ^ (nb0 & 3)) * 8;
      const int b1o = nb1*40 + (fg ^ (nb1 & 3)) * 8;
      short8 fAh[2], fAl[2], fBh[2], fBl[2];
      fAh[0] = *(short8*)&Ah[p][a0o]; fAh[1] = *(short8*)&Ah[p][a1o];
      fAl[0] = *(short8*)&Al[p][a0o]; fAl[1] = *(short8*)&Al[p][a1o];
      fBh[0] = *(short8*)&Bh[p][b0o]; fBh[1] = *(short8*)&Bh[p][b1o];
      fBl[0] = *(short8*)&Bl[p][b0o]; fBl[1] = *(short8*)&Bl[p][b1o];
      #pragma unroll
      for (int sm = 0; sm < 2; sm++)
        #pragma unroll
        for (int sn = 0; sn < 2; sn++){
          acc[sm][sn] = __builtin_amdgcn_mfma_f32_16x16x32_bf16(fAh[sm], fBh[sn], acc[sm][sn], 0, 0, 0);
          acc[sm][sn] = __builtin_amdgcn_mfma_f32_16x16x32_bf16(fAh[sm], fBl[sn], acc[sm][sn], 0, 0, 0);
          acc[sm][sn] = __builtin_amdgcn_mfma_f32_16x16x32_bf16(fAl[sm], fBh[sn], acc[sm][sn], 0, 0, 0);
        }
    }
    p ^= 1;
  }
#undef K7_LD
  const int crow = (lane >> 4) * 4;
  const int ccol = lane & 15;
  #pragma unroll
  for (int sn = 0; sn < 2; sn++){
    const int gcol = c0 + wc*32 + sn*16 + ccol;
    if (gcol < 300){
      #pragma unroll
      for (int sm = 0; sm < 2; sm++){
        const int rbase = m0 + wr*32 + sm*16 + crow;
        #pragma unroll
        for (int r = 0; r < 4; r++)
          out[(size_t)(b*512 + rbase + r) * 300 + gcol] = acc[sm][sn][r] * invs;
      }
    }
  }
}

extern "C" void kernel_launch(void* const* d_in, const int* in_sizes, int n_in,
                              void* d_out, int out_size, void* d_ws, size_t ws_size,
                              hipStream_t stream){
  const float* adj  = (const float*)d_in[0];
  const float* feat = (const float*)d_in[1];
  const float* Ww   = (const float*)d_in[2];
  const float* Wb   = (const float*)d_in[3];
  const float* a1w  = (const float*)d_in[4];
  const float* a1b  = (const float*)d_in[5];
  const float* a2w  = (const float*)d_in[6];
  const float* a2b  = (const float*)d_in[7];
  float* out = (float*)d_out;
  char* ws = (char*)d_ws;

  float* H    = (float*)(ws + 0);           // 4,915,200 B
  float* S    = (float*)(ws + 4915200);     // 2,097,152 B
  float* L    = (float*)(ws + 7012352);     // 8,388,608 B
  float* bm   = (float*)(ws + 15400960);    // 4,096 B
  float* bs   = (float*)(ws + 15405056);    // 4,096 B

  k1_h     <<<dim3(320),      dim3(256), 0, stream>>>(feat, Ww, Wb, H);
  k2_s     <<<dim3(128),      dim3(256), 0, stream>>>(H, a1w, a1b, S);
  k3_logits<<<dim3(8, 16, 8), dim3(256), 0, stream>>>(S, adj, a2w, a2b, L, bm, bs);
  k7_out   <<<dim3(320),      dim3(256), 0, stream>>>(L, H, bm, bs, out);
}

// Round 18
// 77.397 us; speedup vs baseline: 1.0373x; 1.0373x over previous
//
#include <hip/hip_runtime.h>
// R18: revert to R16 exactly (measured best, 77.1us). R17's two-variable change
// (packed split2 + k6-merge) regressed 4%; this recovers the proven state.

#define NEGINF (-1e30f)

typedef __attribute__((ext_vector_type(8))) short short8;
typedef __attribute__((ext_vector_type(4))) float f32x4;

__device__ inline float waveRedSum(float v){
  #pragma unroll
  for (int o = 32; o > 0; o >>= 1) v += __shfl_down(v, o, 64);
  return v;
}
__device__ inline float waveRedMax(float v){
  #pragma unroll
  for (int o = 32; o > 0; o >>= 1) v = fmaxf(v, __shfl_down(v, o, 64));
  return v;
}
__device__ inline float4 f4z(){ return make_float4(0.f,0.f,0.f,0.f); }
#define F4C(v, c) ((c)==0?(v).x:(c)==1?(v).y:(c)==2?(v).z:(v).w)

__device__ inline unsigned short f2bf(float f){
  unsigned u = __float_as_uint(f);
  unsigned r = u + 0x7fffu + ((u >> 16) & 1u);
  return (unsigned short)(r >> 16);
}
__device__ inline float bf2f(unsigned short h){
  return __uint_as_float(((unsigned)h) << 16);
}

// ================= K1: H = feat @ W^T + Wb  [4096 x 300], K=768, MFMA ==============
__global__ __launch_bounds__(256) void k1_h(const float* __restrict__ A,
                                            const float* __restrict__ W,
                                            const float* __restrict__ Wb,
                                            float* __restrict__ H){
  __shared__ short Ah[2][64*40];
  __shared__ short Al[2][64*40];
  __shared__ short Bh[2][64*40];
  __shared__ short Bl[2][64*40];
  const int fid = blockIdx.x;
  const int wl  = (fid & 7) * 40 + (fid >> 3);
  const int y = wl / 5, x = wl % 5;
  const int m0 = y * 64, c0 = x * 64;
  const int t = threadIdx.x;
  const int lane = t & 63, w = t >> 6;
  const int wr = w >> 1, wc = w & 1;
  const int srow = t >> 2, kq = (t & 3) * 8;
  const bool bok = (c0 + srow) < 300;
  const float* Arow = A + (size_t)(m0 + srow) * 768 + kq;
  const float* Wrow = W + (size_t)(c0 + srow) * 768 + kq;
  float4 ra0, ra1, rb0, rb1;
#define K1_LD(kt) { \
    ra0 = *(const float4*)(Arow + (kt)); \
    ra1 = *(const float4*)(Arow + (kt) + 4); \
    rb0 = bok ? *(const float4*)(Wrow + (kt)) : f4z(); \
    rb1 = bok ? *(const float4*)(Wrow + (kt) + 4) : f4z(); }
  K1_LD(0)
  f32x4 acc[2][2];
  #pragma unroll
  for (int i = 0; i < 2; i++)
    #pragma unroll
    for (int j = 0; j < 2; j++)
      acc[i][j] = (f32x4){0.f, 0.f, 0.f, 0.f};
  const int fr = lane & 15;
  const int fk = (lane >> 4) * 8;
  int p = 0;
  for (int tile = 0; tile < 24; ++tile){
    {
      float av[8] = {ra0.x, ra0.y, ra0.z, ra0.w, ra1.x, ra1.y, ra1.z, ra1.w};
      float bv[8] = {rb0.x, rb0.y, rb0.z, rb0.w, rb1.x, rb1.y, rb1.z, rb1.w};
      short8 vah, val_, vbh, vbl;
      #pragma unroll
      for (int i = 0; i < 8; i++){
        unsigned short hh = f2bf(av[i]);
        vah[i] = (short)hh;
        val_[i] = (short)f2bf(av[i] - bf2f(hh));
        unsigned short gh = f2bf(bv[i]);
        vbh[i] = (short)gh;
        vbl[i] = (short)f2bf(bv[i] - bf2f(gh));
      }
      const int o = srow * 40 + kq;
      *(short8*)&Ah[p][o] = vah;
      *(short8*)&Al[p][o] = val_;
      *(short8*)&Bh[p][o] = vbh;
      *(short8*)&Bl[p][o] = vbl;
    }
    __syncthreads();
    if (tile < 23) K1_LD((tile + 1) * 32)
    {
      const int a0o = (wr*32      + fr) * 40 + fk;
      const int a1o = (wr*32 + 16 + fr) * 40 + fk;
      const int b0o = (wc*32      + fr) * 40 + fk;
      const int b1o = (wc*32 + 16 + fr) * 40 + fk;
      short8 fAh[2], fAl[2], fBh[2], fBl[2];
      fAh[0] = *(short8*)&Ah[p][a0o]; fAh[1] = *(short8*)&Ah[p][a1o];
      fAl[0] = *(short8*)&Al[p][a0o]; fAl[1] = *(short8*)&Al[p][a1o];
      fBh[0] = *(short8*)&Bh[p][b0o]; fBh[1] = *(short8*)&Bh[p][b1o];
      fBl[0] = *(short8*)&Bl[p][b0o]; fBl[1] = *(short8*)&Bl[p][b1o];
      #pragma unroll
      for (int sm = 0; sm < 2; sm++)
        #pragma unroll
        for (int sn = 0; sn < 2; sn++){
          acc[sm][sn] = __builtin_amdgcn_mfma_f32_16x16x32_bf16(fAh[sm], fBh[sn], acc[sm][sn], 0, 0, 0);
          acc[sm][sn] = __builtin_amdgcn_mfma_f32_16x16x32_bf16(fAh[sm], fBl[sn], acc[sm][sn], 0, 0, 0);
          acc[sm][sn] = __builtin_amdgcn_mfma_f32_16x16x32_bf16(fAl[sm], fBh[sn], acc[sm][sn], 0, 0, 0);
        }
    }
    p ^= 1;
  }
#undef K1_LD
  const int crow = (lane >> 4) * 4;
  const int ccol = lane & 15;
  #pragma unroll
  for (int sn = 0; sn < 2; sn++){
    const int gcol = c0 + wc*32 + sn*16 + ccol;
    if (gcol < 300){
      const float bi = Wb[gcol];
      #pragma unroll
      for (int sm = 0; sm < 2; sm++){
        const int rbase = m0 + wr*32 + sm*16 + crow;
        #pragma unroll
        for (int r = 0; r < 4; r++)
          H[(size_t)(rbase + r) * 300 + gcol] = acc[sm][sn][r] + bi;
      }
    }
  }
}

// ================= K2: S = H @ Bmat^T (+a1b cols<64)  [4096 x 128], K=300, MFMA ====
__global__ __launch_bounds__(256) void k2_s(const float* __restrict__ Hm,
                                            const float* __restrict__ a1w,
                                            const float* __restrict__ a1b,
                                            float* __restrict__ S){
  __shared__ short Ah[2][64*40];
  __shared__ short Al[2][64*40];
  __shared__ short Bh[2][64*40];
  __shared__ short Bl[2][64*40];
  const int fid = blockIdx.x;
  const int wl  = (fid & 7) * 16 + (fid >> 3);
  const int y = wl >> 1, x = wl & 1;
  const int m0 = y * 64, c0 = x * 64;
  const int t = threadIdx.x;
  const int lane = t & 63, w = t >> 6;
  const int wr = w >> 1, wc = w & 1;
  const int srow = t >> 2, kq = (t & 3) * 8;
  const int brow = c0 + srow;
  const float* Arow = Hm + (size_t)(m0 + srow) * 300;
  const float* Brow = (brow < 64) ? (a1w + (size_t)brow * 600)
                                  : (a1w + (size_t)(brow - 64) * 600 + 300);
  float4 ra0, ra1, rb0, rb1;
#define K2_LD(kt) { \
    const int k = (kt) + kq; \
    ra0 = (k <= 296) ? *(const float4*)(Arow + k)     : f4z(); \
    ra1 = (k <= 292) ? *(const float4*)(Arow + k + 4) : f4z(); \
    rb0 = (k <= 296) ? *(const float4*)(Brow + k)     : f4z(); \
    rb1 = (k <= 292) ? *(const float4*)(Brow + k + 4) : f4z(); }
  K2_LD(0)
  f32x4 acc[2][2];
  #pragma unroll
  for (int i = 0; i < 2; i++)
    #pragma unroll
    for (int j = 0; j < 2; j++)
      acc[i][j] = (f32x4){0.f, 0.f, 0.f, 0.f};
  const int fr = lane & 15;
  const int fk = (lane >> 4) * 8;
  int p = 0;
  for (int tile = 0; tile < 10; ++tile){
    {
      float av[8] = {ra0.x, ra0.y, ra0.z, ra0.w, ra1.x, ra1.y, ra1.z, ra1.w};
      float bv[8] = {rb0.x, rb0.y, rb0.z, rb0.w, rb1.x, rb1.y, rb1.z, rb1.w};
      short8 vah, val_, vbh, vbl;
      #pragma unroll
      for (int i = 0; i < 8; i++){
        unsigned short hh = f2bf(av[i]);
        vah[i] = (short)hh;
        val_[i] = (short)f2bf(av[i] - bf2f(hh));
        unsigned short gh = f2bf(bv[i]);
        vbh[i] = (short)gh;
        vbl[i] = (short)f2bf(bv[i] - bf2f(gh));
      }
      const int o = srow * 40 + kq;
      *(short8*)&Ah[p][o] = vah;
      *(short8*)&Al[p][o] = val_;
      *(short8*)&Bh[p][o] = vbh;
      *(short8*)&Bl[p][o] = vbl;
    }
    __syncthreads();
    if (tile < 9) K2_LD((tile + 1) * 32)
    {
      const int a0o = (wr*32      + fr) * 40 + fk;
      const int a1o = (wr*32 + 16 + fr) * 40 + fk;
      const int b0o = (wc*32      + fr) * 40 + fk;
      const int b1o = (wc*32 + 16 + fr) * 40 + fk;
      short8 fAh[2], fAl[2], fBh[2], fBl[2];
      fAh[0] = *(short8*)&Ah[p][a0o]; fAh[1] = *(short8*)&Ah[p][a1o];
      fAl[0] = *(short8*)&Al[p][a0o]; fAl[1] = *(short8*)&Al[p][a1o];
      fBh[0] = *(short8*)&Bh[p][b0o]; fBh[1] = *(short8*)&Bh[p][b1o];
      fBl[0] = *(short8*)&Bl[p][b0o]; fBl[1] = *(short8*)&Bl[p][b1o];
      #pragma unroll
      for (int sm = 0; sm < 2; sm++)
        #pragma unroll
        for (int sn = 0; sn < 2; sn++){
          acc[sm][sn] = __builtin_amdgcn_mfma_f32_16x16x32_bf16(fAh[sm], fBh[sn], acc[sm][sn], 0, 0, 0);
          acc[sm][sn] = __builtin_amdgcn_mfma_f32_16x16x32_bf16(fAh[sm], fBl[sn], acc[sm][sn], 0, 0, 0);
          acc[sm][sn] = __builtin_amdgcn_mfma_f32_16x16x32_bf16(fAl[sm], fBh[sn], acc[sm][sn], 0, 0, 0);
        }
    }
    p ^= 1;
  }
#undef K2_LD
  const int crow = (lane >> 4) * 4;
  const int ccol = lane & 15;
  #pragma unroll
  for (int sn = 0; sn < 2; sn++){
    const int gcol = c0 + wc*32 + sn*16 + ccol;
    const float bi = (gcol < 64) ? a1b[gcol] : 0.f;
    #pragma unroll
    for (int sm = 0; sm < 2; sm++){
      const int rbase = m0 + wr*32 + sm*16 + crow;
      #pragma unroll
      for (int r = 0; r < 4; r++)
        S[(size_t)(rbase + r) * 128 + gcol] = acc[sm][sn][r] + bi;
    }
  }
}

// ================= K3: logits + mask + per-block (max, sum-exp) =====================
__global__ __launch_bounds__(256) void k3_logits(const float* __restrict__ S,
                                                 const float* __restrict__ adj,
                                                 const float* __restrict__ a2w,
                                                 const float* __restrict__ a2b,
                                                 float* __restrict__ L,
                                                 float* __restrict__ bm,
                                                 float* __restrict__ bs){
  __shared__ float sj_s[64*68];
  __shared__ float w_s[64];
  __shared__ float redm[4];
  __shared__ float reds[4];
  __shared__ float smax;
  const int b  = blockIdx.z;
  const int i0 = blockIdx.y * 32;
  const int j0 = blockIdx.x * 64;
  const int t  = threadIdx.x;
  const int j = t & 63, iq = t >> 6;
  if (t < 16) *(float4*)&w_s[t*4] = *(const float4*)&a2w[t*4];
  #pragma unroll
  for (int q = 0; q < 4; q++){
    int c = t + q*256; int r = c >> 4, c4 = c & 15;
    *(float4*)&sj_s[r*68 + c4*4] = *(const float4*)&S[(size_t)(b*512 + j0 + r)*128 + 64 + c4*4];
  }
  float vsi[8];
  #pragma unroll
  for (int r = 0; r < 8; r++)
    vsi[r] = S[(size_t)(b*512 + i0 + r*4 + iq) * 128 + j];
  __syncthreads();
  const float a2bv = a2b[0];
  float accA[8][4];
  #pragma unroll
  for (int r = 0; r < 8; r++)
    #pragma unroll
    for (int c = 0; c < 4; c++) accA[r][c] = 0.f;
  #pragma unroll
  for (int k4 = 0; k4 < 16; k4++){
    const float4 sj4 = *(const float4*)&sj_s[j*68 + k4*4];
    const float4 w4  = *(const float4*)&w_s[k4*4];
    #pragma unroll
    for (int c = 0; c < 4; c++){
      const int k = k4*4 + c;
      const float sjc = F4C(sj4, c);
      const float wc  = F4C(w4, c);
      #pragma unroll
      for (int r = 0; r < 8; r++){
        const float s = __int_as_float(__builtin_amdgcn_readlane(__float_as_int(vsi[r]), k));
        accA[r][c] += fmaxf(s + sjc, 0.f) * wc;
      }
    }
  }
  float l_arr[8];
  float locmax = -3e38f;
  #pragma unroll
  for (int r = 0; r < 8; r++){
    const int i = r*4 + iq;
    float e = ((accA[r][0] + accA[r][1]) + (accA[r][2] + accA[r][3])) + a2bv;
    e = (e >= 0.f) ? e : 0.01f * e;
    size_t idxg = (size_t)(b*512 + i0 + i)*512 + j0 + j;
    float l = (adj[idxg] != 0.f) ? e : NEGINF;
    l_arr[r] = l;
    L[idxg] = l;
    locmax = fmaxf(locmax, l);
  }
  float m = waveRedMax(locmax);
  if ((t & 63) == 0) redm[t >> 6] = m;
  __syncthreads();
  if (t == 0) smax = fmaxf(fmaxf(redm[0], redm[1]), fmaxf(redm[2], redm[3]));
  __syncthreads();
  const float mb = smax;
  float sacc = 0.f;
  #pragma unroll
  for (int r = 0; r < 8; r++) sacc += __expf(l_arr[r] - mb);
  sacc = waveRedSum(sacc);
  if ((t & 63) == 0) reds[t >> 6] = sacc;
  __syncthreads();
  if (t == 0){
    const int bid = (blockIdx.z * 16 + blockIdx.y) * 8 + blockIdx.x;
    bm[bid] = mb;
    bs[bid] = (reds[0] + reds[1]) + (reds[2] + reds[3]);
  }
}

// ================= K6: combine per-block (m,s) -> per-batch (maxg, sums) ============
__global__ __launch_bounds__(128) void k6_red(const float* __restrict__ bm,
                                              const float* __restrict__ bs,
                                              float* __restrict__ sums,
                                              float* __restrict__ maxg){
  const int b = blockIdx.x, t = threadIdx.x;
  const float m = bm[b*128 + t];
  float mm = waveRedMax(m);
  __shared__ float r2m[2];
  __shared__ float mgs;
  if ((t & 63) == 0) r2m[t >> 6] = mm;
  __syncthreads();
  if (t == 0) mgs = fmaxf(r2m[0], r2m[1]);
  __syncthreads();
  const float mg = mgs;
  float v = bs[b*128 + t] * __expf(m - mg);
  v = waveRedSum(v);
  __shared__ float r2s[2];
  if ((t & 63) == 0) r2s[t >> 6] = v;
  __syncthreads();
  if (t == 0){ sums[b] = r2s[0] + r2s[1]; maxg[b] = mg; }
}

// ================= K7: out = (exp(L-maxg) @ H) / sums, MFMA split-bf16 ==============
__global__ __launch_bounds__(256) void k7_out(const float* __restrict__ Lr,
                                              const float* __restrict__ Hm,
                                              const float* __restrict__ sums,
                                              const float* __restrict__ maxg,
                                              float* __restrict__ out){
  __shared__ short Ah[2][64*40];
  __shared__ short Al[2][64*40];
  __shared__ short Bh[2][64*40];
  __shared__ short Bl[2][64*40];
  const int fid = blockIdx.x;
  const int b = fid & 7, idx = fid >> 3;
  const int y = idx / 5, x = idx % 5;
  const int m0 = y * 64, c0 = x * 64;
  const int t = threadIdx.x;
  const int lane = t & 63, wv = t >> 6;
  const int wr = wv >> 1, wc = wv & 1;
  const float mx = maxg[b];
  const int srow = t >> 2, kq = (t & 3) * 8;
  const float* Lrow = Lr + (size_t)(b*512 + m0 + srow) * 512 + kq;
  const int tk = t >> 4, tn = t & 15;
  const int k0 = tk * 2, n0 = tn * 4;
  const int gcolB = c0 + n0;
  const bool bok = gcolB < 300;
  float4 ra0, ra1, hb0, hb1;
#define K7_LD(kt) { \
    ra0 = *(const float4*)(Lrow + (kt)); \
    ra1 = *(const float4*)(Lrow + (kt) + 4); \
    const float* hr = Hm + (size_t)(b*512 + (kt) + k0) * 300 + gcolB; \
    hb0 = bok ? *(const float4*)hr : f4z(); \
    hb1 = bok ? *(const float4*)(hr + 300) : f4z(); }
  K7_LD(0)
  f32x4 acc[2][2];
  #pragma unroll
  for (int i = 0; i < 2; i++)
    #pragma unroll
    for (int jj = 0; jj < 2; jj++)
      acc[i][jj] = (f32x4){0.f, 0.f, 0.f, 0.f};
  const int fr = lane & 15;
  const int fg = lane >> 4;
  const int fk = fg * 8;
  int p = 0;
  for (int tile = 0; tile < 16; ++tile){
    {
      float av[8] = {ra0.x, ra0.y, ra0.z, ra0.w, ra1.x, ra1.y, ra1.z, ra1.w};
      short8 vah, val_;
      #pragma unroll
      for (int i = 0; i < 8; i++){
        const float e = __expf(av[i] - mx);
        unsigned short hh = f2bf(e);
        vah[i] = (short)hh;
        val_[i] = (short)f2bf(e - bf2f(hh));
      }
      const int o = srow * 40 + kq;
      *(short8*)&Ah[p][o] = vah;
      *(short8*)&Al[p][o] = val_;
      #pragma unroll
      for (int i = 0; i < 4; i++){
        const float v0 = F4C(hb0, i), v1 = F4C(hb1, i);
        const unsigned short h0 = f2bf(v0), h1 = f2bf(v1);
        const unsigned short l0 = f2bf(v0 - bf2f(h0)), l1 = f2bf(v1 - bf2f(h1));
        const int n = n0 + i;
        const int kbs = (k0 >> 3) ^ (n & 3);
        const int soff = n*40 + kbs*8 + (k0 & 7);
        *(unsigned*)&Bh[p][soff] = (unsigned)h0 | ((unsigned)h1 << 16);
        *(unsigned*)&Bl[p][soff] = (unsigned)l0 | ((unsigned)l1 << 16);
      }
    }
    __syncthreads();
    if (tile < 15) K7_LD((tile + 1) * 32)
    {
      const int a0o = (wr*32      + fr) * 40 + fk;
      const int a1o = (wr*32 + 16 + fr) * 40 + fk;
      const int nb0 = wc*32      + fr;
      const int nb1 = wc*32 + 16 + fr;
      const int b0o = nb0*40 + (fg ^ (nb0 & 3)) * 8;
      const int b1o = nb1*40 + (fg ^ (nb1 & 3)) * 8;
      short8 fAh[2], fAl[2], fBh[2], fBl[2];
      fAh[0] = *(short8*)&Ah[p][a0o]; fAh[1] = *(short8*)&Ah[p][a1o];
      fAl[0] = *(short8*)&Al[p][a0o]; fAl[1] = *(short8*)&Al[p][a1o];
      fBh[0] = *(short8*)&Bh[p][b0o]; fBh[1] = *(short8*)&Bh[p][b1o];
      fBl[0] = *(short8*)&Bl[p][b0o]; fBl[1] = *(short8*)&Bl[p][b1o];
      #pragma unroll
      for (int sm = 0; sm < 2; sm++)
        #pragma unroll
        for (int sn = 0; sn < 2; sn++){
          acc[sm][sn] = __builtin_amdgcn_mfma_f32_16x16x32_bf16(fAh[sm], fBh[sn], acc[sm][sn], 0, 0, 0);
          acc[sm][sn] = __builtin_amdgcn_mfma_f32_16x16x32_bf16(fAh[sm], fBl[sn], acc[sm][sn], 0, 0, 0);
          acc[sm][sn] = __builtin_amdgcn_mfma_f32_16x16x32_bf16(fAl[sm], fBh[sn], acc[sm][sn], 0, 0, 0);
        }
    }
    p ^= 1;
  }
#undef K7_LD
  const float invs = 1.0f / sums[b];
  const int crow = (lane >> 4) * 4;
  const int ccol = lane & 15;
  #pragma unroll
  for (int sn = 0; sn < 2; sn++){
    const int gcol = c0 + wc*32 + sn*16 + ccol;
    if (gcol < 300){
      #pragma unroll
      for (int sm = 0; sm < 2; sm++){
        const int rbase = m0 + wr*32 + sm*16 + crow;
        #pragma unroll
        for (int r = 0; r < 4; r++)
          out[(size_t)(b*512 + rbase + r) * 300 + gcol] = acc[sm][sn][r] * invs;
      }
    }
  }
}

extern "C" void kernel_launch(void* const* d_in, const int* in_sizes, int n_in,
                              void* d_out, int out_size, void* d_ws, size_t ws_size,
                              hipStream_t stream){
  const float* adj  = (const float*)d_in[0];
  const float* feat = (const float*)d_in[1];
  const float* Ww   = (const float*)d_in[2];
  const float* Wb   = (const float*)d_in[3];
  const float* a1w  = (const float*)d_in[4];
  const float* a1b  = (const float*)d_in[5];
  const float* a2w  = (const float*)d_in[6];
  const float* a2b  = (const float*)d_in[7];
  float* out = (float*)d_out;
  char* ws = (char*)d_ws;

  float* H    = (float*)(ws + 0);           // 4,915,200 B
  float* S    = (float*)(ws + 4915200);     // 2,097,152 B
  float* L    = (float*)(ws + 7012352);     // 8,388,608 B
  float* bm   = (float*)(ws + 15400960);    // 4,096 B
  float* bs   = (float*)(ws + 15405056);    // 4,096 B
  float* sums = (float*)(ws + 15409152);    // 32 B
  float* maxg = (float*)(ws + 15409216);    // 32 B

  k1_h     <<<dim3(320),      dim3(256), 0, stream>>>(feat, Ww, Wb, H);
  k2_s     <<<dim3(128),      dim3(256), 0, stream>>>(H, a1w, a1b, S);
  k3_logits<<<dim3(8, 16, 8), dim3(256), 0, stream>>>(S, adj, a2w, a2b, L, bm, bs);
  k6_red   <<<dim3(8),        dim3(128), 0, stream>>>(bm, bs, sums, maxg);
  k7_out   <<<dim3(320),      dim3(256), 0, stream>>>(L, H, sums, maxg, out);
}

// Round 19
// 75.729 us; speedup vs baseline: 1.0601x; 1.0220x over previous
//
#include <hip/hip_runtime.h>
// R19: R18 + ONE change: k6 merged into k7 (per-block bm/bs reduction before the
// GEMM). All staging keeps the proven manual f2bf. Tests whether R17's regression
// was the split2 conversion (suspected) or the k6-merge.

#define NEGINF (-1e30f)

typedef __attribute__((ext_vector_type(8))) short short8;
typedef __attribute__((ext_vector_type(4))) float f32x4;

__device__ inline float waveRedSum(float v){
  #pragma unroll
  for (int o = 32; o > 0; o >>= 1) v += __shfl_down(v, o, 64);
  return v;
}
__device__ inline float waveRedMax(float v){
  #pragma unroll
  for (int o = 32; o > 0; o >>= 1) v = fmaxf(v, __shfl_down(v, o, 64));
  return v;
}
__device__ inline float4 f4z(){ return make_float4(0.f,0.f,0.f,0.f); }
#define F4C(v, c) ((c)==0?(v).x:(c)==1?(v).y:(c)==2?(v).z:(v).w)

__device__ inline unsigned short f2bf(float f){
  unsigned u = __float_as_uint(f);
  unsigned r = u + 0x7fffu + ((u >> 16) & 1u);
  return (unsigned short)(r >> 16);
}
__device__ inline float bf2f(unsigned short h){
  return __uint_as_float(((unsigned)h) << 16);
}

// ================= K1: H = feat @ W^T + Wb  [4096 x 300], K=768, MFMA ==============
__global__ __launch_bounds__(256) void k1_h(const float* __restrict__ A,
                                            const float* __restrict__ W,
                                            const float* __restrict__ Wb,
                                            float* __restrict__ H){
  __shared__ short Ah[2][64*40];
  __shared__ short Al[2][64*40];
  __shared__ short Bh[2][64*40];
  __shared__ short Bl[2][64*40];
  const int fid = blockIdx.x;
  const int wl  = (fid & 7) * 40 + (fid >> 3);
  const int y = wl / 5, x = wl % 5;
  const int m0 = y * 64, c0 = x * 64;
  const int t = threadIdx.x;
  const int lane = t & 63, w = t >> 6;
  const int wr = w >> 1, wc = w & 1;
  const int srow = t >> 2, kq = (t & 3) * 8;
  const bool bok = (c0 + srow) < 300;
  const float* Arow = A + (size_t)(m0 + srow) * 768 + kq;
  const float* Wrow = W + (size_t)(c0 + srow) * 768 + kq;
  float4 ra0, ra1, rb0, rb1;
#define K1_LD(kt) { \
    ra0 = *(const float4*)(Arow + (kt)); \
    ra1 = *(const float4*)(Arow + (kt) + 4); \
    rb0 = bok ? *(const float4*)(Wrow + (kt)) : f4z(); \
    rb1 = bok ? *(const float4*)(Wrow + (kt) + 4) : f4z(); }
  K1_LD(0)
  f32x4 acc[2][2];
  #pragma unroll
  for (int i = 0; i < 2; i++)
    #pragma unroll
    for (int j = 0; j < 2; j++)
      acc[i][j] = (f32x4){0.f, 0.f, 0.f, 0.f};
  const int fr = lane & 15;
  const int fk = (lane >> 4) * 8;
  int p = 0;
  for (int tile = 0; tile < 24; ++tile){
    {
      float av[8] = {ra0.x, ra0.y, ra0.z, ra0.w, ra1.x, ra1.y, ra1.z, ra1.w};
      float bv[8] = {rb0.x, rb0.y, rb0.z, rb0.w, rb1.x, rb1.y, rb1.z, rb1.w};
      short8 vah, val_, vbh, vbl;
      #pragma unroll
      for (int i = 0; i < 8; i++){
        unsigned short hh = f2bf(av[i]);
        vah[i] = (short)hh;
        val_[i] = (short)f2bf(av[i] - bf2f(hh));
        unsigned short gh = f2bf(bv[i]);
        vbh[i] = (short)gh;
        vbl[i] = (short)f2bf(bv[i] - bf2f(gh));
      }
      const int o = srow * 40 + kq;
      *(short8*)&Ah[p][o] = vah;
      *(short8*)&Al[p][o] = val_;
      *(short8*)&Bh[p][o] = vbh;
      *(short8*)&Bl[p][o] = vbl;
    }
    __syncthreads();
    if (tile < 23) K1_LD((tile + 1) * 32)
    {
      const int a0o = (wr*32      + fr) * 40 + fk;
      const int a1o = (wr*32 + 16 + fr) * 40 + fk;
      const int b0o = (wc*32      + fr) * 40 + fk;
      const int b1o = (wc*32 + 16 + fr) * 40 + fk;
      short8 fAh[2], fAl[2], fBh[2], fBl[2];
      fAh[0] = *(short8*)&Ah[p][a0o]; fAh[1] = *(short8*)&Ah[p][a1o];
      fAl[0] = *(short8*)&Al[p][a0o]; fAl[1] = *(short8*)&Al[p][a1o];
      fBh[0] = *(short8*)&Bh[p][b0o]; fBh[1] = *(short8*)&Bh[p][b1o];
      fBl[0] = *(short8*)&Bl[p][b0o]; fBl[1] = *(short8*)&Bl[p][b1o];
      #pragma unroll
      for (int sm = 0; sm < 2; sm++)
        #pragma unroll
        for (int sn = 0; sn < 2; sn++){
          acc[sm][sn] = __builtin_amdgcn_mfma_f32_16x16x32_bf16(fAh[sm], fBh[sn], acc[sm][sn], 0, 0, 0);
          acc[sm][sn] = __builtin_amdgcn_mfma_f32_16x16x32_bf16(fAh[sm], fBl[sn], acc[sm][sn], 0, 0, 0);
          acc[sm][sn] = __builtin_amdgcn_mfma_f32_16x16x32_bf16(fAl[sm], fBh[sn], acc[sm][sn], 0, 0, 0);
        }
    }
    p ^= 1;
  }
#undef K1_LD
  const int crow = (lane >> 4) * 4;
  const int ccol = lane & 15;
  #pragma unroll
  for (int sn = 0; sn < 2; sn++){
    const int gcol = c0 + wc*32 + sn*16 + ccol;
    if (gcol < 300){
      const float bi = Wb[gcol];
      #pragma unroll
      for (int sm = 0; sm < 2; sm++){
        const int rbase = m0 + wr*32 + sm*16 + crow;
        #pragma unroll
        for (int r = 0; r < 4; r++)
          H[(size_t)(rbase + r) * 300 + gcol] = acc[sm][sn][r] + bi;
      }
    }
  }
}

// ================= K2: S = H @ Bmat^T (+a1b cols<64)  [4096 x 128], K=300, MFMA ====
__global__ __launch_bounds__(256) void k2_s(const float* __restrict__ Hm,
                                            const float* __restrict__ a1w,
                                            const float* __restrict__ a1b,
                                            float* __restrict__ S){
  __shared__ short Ah[2][64*40];
  __shared__ short Al[2][64*40];
  __shared__ short Bh[2][64*40];
  __shared__ short Bl[2][64*40];
  const int fid = blockIdx.x;
  const int wl  = (fid & 7) * 16 + (fid >> 3);
  const int y = wl >> 1, x = wl & 1;
  const int m0 = y * 64, c0 = x * 64;
  const int t = threadIdx.x;
  const int lane = t & 63, w = t >> 6;
  const int wr = w >> 1, wc = w & 1;
  const int srow = t >> 2, kq = (t & 3) * 8;
  const int brow = c0 + srow;
  const float* Arow = Hm + (size_t)(m0 + srow) * 300;
  const float* Brow = (brow < 64) ? (a1w + (size_t)brow * 600)
                                  : (a1w + (size_t)(brow - 64) * 600 + 300);
  float4 ra0, ra1, rb0, rb1;
#define K2_LD(kt) { \
    const int k = (kt) + kq; \
    ra0 = (k <= 296) ? *(const float4*)(Arow + k)     : f4z(); \
    ra1 = (k <= 292) ? *(const float4*)(Arow + k + 4) : f4z(); \
    rb0 = (k <= 296) ? *(const float4*)(Brow + k)     : f4z(); \
    rb1 = (k <= 292) ? *(const float4*)(Brow + k + 4) : f4z(); }
  K2_LD(0)
  f32x4 acc[2][2];
  #pragma unroll
  for (int i = 0; i < 2; i++)
    #pragma unroll
    for (int j = 0; j < 2; j++)
      acc[i][j] = (f32x4){0.f, 0.f, 0.f, 0.f};
  const int fr = lane & 15;
  const int fk = (lane >> 4) * 8;
  int p = 0;
  for (int tile = 0; tile < 10; ++tile){
    {
      float av[8] = {ra0.x, ra0.y, ra0.z, ra0.w, ra1.x, ra1.y, ra1.z, ra1.w};
      float bv[8] = {rb0.x, rb0.y, rb0.z, rb0.w, rb1.x, rb1.y, rb1.z, rb1.w};
      short8 vah, val_, vbh, vbl;
      #pragma unroll
      for (int i = 0; i < 8; i++){
        unsigned short hh = f2bf(av[i]);
        vah[i] = (short)hh;
        val_[i] = (short)f2bf(av[i] - bf2f(hh));
        unsigned short gh = f2bf(bv[i]);
        vbh[i] = (short)gh;
        vbl[i] = (short)f2bf(bv[i] - bf2f(gh));
      }
      const int o = srow * 40 + kq;
      *(short8*)&Ah[p][o] = vah;
      *(short8*)&Al[p][o] = val_;
      *(short8*)&Bh[p][o] = vbh;
      *(short8*)&Bl[p][o] = vbl;
    }
    __syncthreads();
    if (tile < 9) K2_LD((tile + 1) * 32)
    {
      const int a0o = (wr*32      + fr) * 40 + fk;
      const int a1o = (wr*32 + 16 + fr) * 40 + fk;
      const int b0o = (wc*32      + fr) * 40 + fk;
      const int b1o = (wc*32 + 16 + fr) * 40 + fk;
      short8 fAh[2], fAl[2], fBh[2], fBl[2];
      fAh[0] = *(short8*)&Ah[p][a0o]; fAh[1] = *(short8*)&Ah[p][a1o];
      fAl[0] = *(short8*)&Al[p][a0o]; fAl[1] = *(short8*)&Al[p][a1o];
      fBh[0] = *(short8*)&Bh[p][b0o]; fBh[1] = *(short8*)&Bh[p][b1o];
      fBl[0] = *(short8*)&Bl[p][b0o]; fBl[1] = *(short8*)&Bl[p][b1o];
      #pragma unroll
      for (int sm = 0; sm < 2; sm++)
        #pragma unroll
        for (int sn = 0; sn < 2; sn++){
          acc[sm][sn] = __builtin_amdgcn_mfma_f32_16x16x32_bf16(fAh[sm], fBh[sn], acc[sm][sn], 0, 0, 0);
          acc[sm][sn] = __builtin_amdgcn_mfma_f32_16x16x32_bf16(fAh[sm], fBl[sn], acc[sm][sn], 0, 0, 0);
          acc[sm][sn] = __builtin_amdgcn_mfma_f32_16x16x32_bf16(fAl[sm], fBh[sn], acc[sm][sn], 0, 0, 0);
        }
    }
    p ^= 1;
  }
#undef K2_LD
  const int crow = (lane >> 4) * 4;
  const int ccol = lane & 15;
  #pragma unroll
  for (int sn = 0; sn < 2; sn++){
    const int gcol = c0 + wc*32 + sn*16 + ccol;
    const float bi = (gcol < 64) ? a1b[gcol] : 0.f;
    #pragma unroll
    for (int sm = 0; sm < 2; sm++){
      const int rbase = m0 + wr*32 + sm*16 + crow;
      #pragma unroll
      for (int r = 0; r < 4; r++)
        S[(size_t)(rbase + r) * 128 + gcol] = acc[sm][sn][r] + bi;
    }
  }
}

// ================= K3: logits + mask + per-block (max, sum-exp) =====================
__global__ __launch_bounds__(256) void k3_logits(const float* __restrict__ S,
                                                 const float* __restrict__ adj,
                                                 const float* __restrict__ a2w,
                                                 const float* __restrict__ a2b,
                                                 float* __restrict__ L,
                                                 float* __restrict__ bm,
                                                 float* __restrict__ bs){
  __shared__ float sj_s[64*68];
  __shared__ float w_s[64];
  __shared__ float redm[4];
  __shared__ float reds[4];
  __shared__ float smax;
  const int b  = blockIdx.z;
  const int i0 = blockIdx.y * 32;
  const int j0 = blockIdx.x * 64;
  const int t  = threadIdx.x;
  const int j = t & 63, iq = t >> 6;
  if (t < 16) *(float4*)&w_s[t*4] = *(const float4*)&a2w[t*4];
  #pragma unroll
  for (int q = 0; q < 4; q++){
    int c = t + q*256; int r = c >> 4, c4 = c & 15;
    *(float4*)&sj_s[r*68 + c4*4] = *(const float4*)&S[(size_t)(b*512 + j0 + r)*128 + 64 + c4*4];
  }
  float vsi[8];
  #pragma unroll
  for (int r = 0; r < 8; r++)
    vsi[r] = S[(size_t)(b*512 + i0 + r*4 + iq) * 128 + j];
  __syncthreads();
  const float a2bv = a2b[0];
  float accA[8][4];
  #pragma unroll
  for (int r = 0; r < 8; r++)
    #pragma unroll
    for (int c = 0; c < 4; c++) accA[r][c] = 0.f;
  #pragma unroll
  for (int k4 = 0; k4 < 16; k4++){
    const float4 sj4 = *(const float4*)&sj_s[j*68 + k4*4];
    const float4 w4  = *(const float4*)&w_s[k4*4];
    #pragma unroll
    for (int c = 0; c < 4; c++){
      const int k = k4*4 + c;
      const float sjc = F4C(sj4, c);
      const float wc  = F4C(w4, c);
      #pragma unroll
      for (int r = 0; r < 8; r++){
        const float s = __int_as_float(__builtin_amdgcn_readlane(__float_as_int(vsi[r]), k));
        accA[r][c] += fmaxf(s + sjc, 0.f) * wc;
      }
    }
  }
  float l_arr[8];
  float locmax = -3e38f;
  #pragma unroll
  for (int r = 0; r < 8; r++){
    const int i = r*4 + iq;
    float e = ((accA[r][0] + accA[r][1]) + (accA[r][2] + accA[r][3])) + a2bv;
    e = (e >= 0.f) ? e : 0.01f * e;
    size_t idxg = (size_t)(b*512 + i0 + i)*512 + j0 + j;
    float l = (adj[idxg] != 0.f) ? e : NEGINF;
    l_arr[r] = l;
    L[idxg] = l;
    locmax = fmaxf(locmax, l);
  }
  float m = waveRedMax(locmax);
  if ((t & 63) == 0) redm[t >> 6] = m;
  __syncthreads();
  if (t == 0) smax = fmaxf(fmaxf(redm[0], redm[1]), fmaxf(redm[2], redm[3]));
  __syncthreads();
  const float mb = smax;
  float sacc = 0.f;
  #pragma unroll
  for (int r = 0; r < 8; r++) sacc += __expf(l_arr[r] - mb);
  sacc = waveRedSum(sacc);
  if ((t & 63) == 0) reds[t >> 6] = sacc;
  __syncthreads();
  if (t == 0){
    const int bid = (blockIdx.z * 16 + blockIdx.y) * 8 + blockIdx.x;
    bm[bid] = mb;
    bs[bid] = (reds[0] + reds[1]) + (reds[2] + reds[3]);
  }
}

// ================= K7: out = (exp(L-mx) @ H) * inv(sum); in-block k6 reduction ======
__global__ __launch_bounds__(256) void k7_out(const float* __restrict__ Lr,
                                              const float* __restrict__ Hm,
                                              const float* __restrict__ bm,
                                              const float* __restrict__ bs,
                                              float* __restrict__ out){
  __shared__ short Ah[2][64*40];
  __shared__ short Al[2][64*40];
  __shared__ short Bh[2][64*40];
  __shared__ short Bl[2][64*40];
  __shared__ float rmx[4], rsm[4];
  const int fid = blockIdx.x;
  const int b = fid & 7, idx = fid >> 3;
  const int y = idx / 5, x = idx % 5;
  const int m0 = y * 64, c0 = x * 64;
  const int t = threadIdx.x;
  const int lane = t & 63, wv = t >> 6;
  const int wr = wv >> 1, wc = wv & 1;
  // ---- in-block reduction of (bm, bs) for batch b (replaces k6) ----
  const float mload = (t < 128) ? bm[b*128 + t] : -3e38f;
  float mm = waveRedMax(mload);
  if (lane == 0) rmx[wv] = mm;
  __syncthreads();
  const float mx = fmaxf(fmaxf(rmx[0], rmx[1]), fmaxf(rmx[2], rmx[3]));
  float sload = (t < 128) ? bs[b*128 + t] * __expf(mload - mx) : 0.f;
  float ss = waveRedSum(sload);
  if (lane == 0) rsm[wv] = ss;
  __syncthreads();
  const float invs = 1.0f / ((rsm[0] + rsm[1]) + (rsm[2] + rsm[3]));
  // ---- GEMM (identical to R18's k7) ----
  const int srow = t >> 2, kq = (t & 3) * 8;
  const float* Lrow = Lr + (size_t)(b*512 + m0 + srow) * 512 + kq;
  const int tk = t >> 4, tn = t & 15;
  const int k0 = tk * 2, n0 = tn * 4;
  const int gcolB = c0 + n0;
  const bool bok = gcolB < 300;
  float4 ra0, ra1, hb0, hb1;
#define K7_LD(kt) { \
    ra0 = *(const float4*)(Lrow + (kt)); \
    ra1 = *(const float4*)(Lrow + (kt) + 4); \
    const float* hr = Hm + (size_t)(b*512 + (kt) + k0) * 300 + gcolB; \
    hb0 = bok ? *(const float4*)hr : f4z(); \
    hb1 = bok ? *(const float4*)(hr + 300) : f4z(); }
  K7_LD(0)
  f32x4 acc[2][2];
  #pragma unroll
  for (int i = 0; i < 2; i++)
    #pragma unroll
    for (int jj = 0; jj < 2; jj++)
      acc[i][jj] = (f32x4){0.f, 0.f, 0.f, 0.f};
  const int fr = lane & 15;
  const int fg = lane >> 4;
  const int fk = fg * 8;
  int p = 0;
  for (int tile = 0; tile < 16; ++tile){
    {
      float av[8] = {ra0.x, ra0.y, ra0.z, ra0.w, ra1.x, ra1.y, ra1.z, ra1.w};
      short8 vah, val_;
      #pragma unroll
      for (int i = 0; i < 8; i++){
        const float e = __expf(av[i] - mx);
        unsigned short hh = f2bf(e);
        vah[i] = (short)hh;
        val_[i] = (short)f2bf(e - bf2f(hh));
      }
      const int o = srow * 40 + kq;
      *(short8*)&Ah[p][o] = vah;
      *(short8*)&Al[p][o] = val_;
      #pragma unroll
      for (int i = 0; i < 4; i++){
        const float v0 = F4C(hb0, i), v1 = F4C(hb1, i);
        const unsigned short h0 = f2bf(v0), h1 = f2bf(v1);
        const unsigned short l0 = f2bf(v0 - bf2f(h0)), l1 = f2bf(v1 - bf2f(h1));
        const int n = n0 + i;
        const int kbs = (k0 >> 3) ^ (n & 3);
        const int soff = n*40 + kbs*8 + (k0 & 7);
        *(unsigned*)&Bh[p][soff] = (unsigned)h0 | ((unsigned)h1 << 16);
        *(unsigned*)&Bl[p][soff] = (unsigned)l0 | ((unsigned)l1 << 16);
      }
    }
    __syncthreads();
    if (tile < 15) K7_LD((tile + 1) * 32)
    {
      const int a0o = (wr*32      + fr) * 40 + fk;
      const int a1o = (wr*32 + 16 + fr) * 40 + fk;
      const int nb0 = wc*32      + fr;
      const int nb1 = wc*32 + 16 + fr;
      const int b0o = nb0*40 + (fg ^ (nb0 & 3)) * 8;
      const int b1o = nb1*40 + (fg ^ (nb1 & 3)) * 8;
      short8 fAh[2], fAl[2], fBh[2], fBl[2];
      fAh[0] = *(short8*)&Ah[p][a0o]; fAh[1] = *(short8*)&Ah[p][a1o];
      fAl[0] = *(short8*)&Al[p][a0o]; fAl[1] = *(short8*)&Al[p][a1o];
      fBh[0] = *(short8*)&Bh[p][b0o]; fBh[1] = *(short8*)&Bh[p][b1o];
      fBl[0] = *(short8*)&Bl[p][b0o]; fBl[1] = *(short8*)&Bl[p][b1o];
      #pragma unroll
      for (int sm = 0; sm < 2; sm++)
        #pragma unroll
        for (int sn = 0; sn < 2; sn++){
          acc[sm][sn] = __builtin_amdgcn_mfma_f32_16x16x32_bf16(fAh[sm], fBh[sn], acc[sm][sn], 0, 0, 0);
          acc[sm][sn] = __builtin_amdgcn_mfma_f32_16x16x32_bf16(fAh[sm], fBl[sn], acc[sm][sn], 0, 0, 0);
          acc[sm][sn] = __builtin_amdgcn_mfma_f32_16x16x32_bf16(fAl[sm], fBh[sn], acc[sm][sn], 0, 0, 0);
        }
    }
    p ^= 1;
  }
#undef K7_LD
  const int crow = (lane >> 4) * 4;
  const int ccol = lane & 15;
  #pragma unroll
  for (int sn = 0; sn < 2; sn++){
    const int gcol = c0 + wc*32 + sn*16 + ccol;
    if (gcol < 300){
      #pragma unroll
      for (int sm = 0; sm < 2; sm++){
        const int rbase = m0 + wr*32 + sm*16 + crow;
        #pragma unroll
        for (int r = 0; r < 4; r++)
          out[(size_t)(b*512 + rbase + r) * 300 + gcol] = acc[sm][sn][r] * invs;
      }
    }
  }
}

extern "C" void kernel_launch(void* const* d_in, const int* in_sizes, int n_in,
                              void* d_out, int out_size, void* d_ws, size_t ws_size,
                              hipStream_t stream){
  const float* adj  = (const float*)d_in[0];
  const float* feat = (const float*)d_in[1];
  const float* Ww   = (const float*)d_in[2];
  const float* Wb   = (const float*)d_in[3];
  const float* a1w  = (const float*)d_in[4];
  const float* a1b  = (const float*)d_in[5];
  const float* a2w  = (const float*)d_in[6];
  const float* a2b  = (const float*)d_in[7];
  float* out = (float*)d_out;
  char* ws = (char*)d_ws;

  float* H    = (float*)(ws + 0);           // 4,915,200 B
  float* S    = (float*)(ws + 4915200);     // 2,097,152 B
  float* L    = (float*)(ws + 7012352);     // 8,388,608 B
  float* bm   = (float*)(ws + 15400960);    // 4,096 B
  float* bs   = (float*)(ws + 15405056);    // 4,096 B

  k1_h     <<<dim3(320),      dim3(256), 0, stream>>>(feat, Ww, Wb, H);
  k2_s     <<<dim3(128),      dim3(256), 0, stream>>>(H, a1w, a1b, S);
  k3_logits<<<dim3(8, 16, 8), dim3(256), 0, stream>>>(S, adj, a2w, a2b, L, bm, bs);
  k7_out   <<<dim3(320),      dim3(256), 0, stream>>>(L, H, bm, bs, out);
}

// Round 22
// 70.589 us; speedup vs baseline: 1.1373x; 1.0728x over previous
//
#include <hip/hip_runtime.h>
// R22: compile fix for R21 — hf2 is defined as decltype(cvt_pkrtz) (__fp16 vec2),
// making cvt_pkrtz/arithmetic/fdot2 type-identical. k3 packed-fp16 inner loop;
// k1/k2/k7 byte-identical to R19.

#define NEGINF (-1e30f)

typedef __attribute__((ext_vector_type(8))) short short8;
typedef __attribute__((ext_vector_type(4))) float f32x4;
typedef decltype(__builtin_amdgcn_cvt_pkrtz(0.0f, 0.0f)) hf2;

__device__ inline float waveRedSum(float v){
  #pragma unroll
  for (int o = 32; o > 0; o >>= 1) v += __shfl_down(v, o, 64);
  return v;
}
__device__ inline float waveRedMax(float v){
  #pragma unroll
  for (int o = 32; o > 0; o >>= 1) v = fmaxf(v, __shfl_down(v, o, 64));
  return v;
}
__device__ inline float4 f4z(){ return make_float4(0.f,0.f,0.f,0.f); }
#define F4C(v, c) ((c)==0?(v).x:(c)==1?(v).y:(c)==2?(v).z:(v).w)

__device__ inline unsigned short f2bf(float f){
  unsigned u = __float_as_uint(f);
  unsigned r = u + 0x7fffu + ((u >> 16) & 1u);
  return (unsigned short)(r >> 16);
}
__device__ inline float bf2f(unsigned short h){
  return __uint_as_float(((unsigned)h) << 16);
}
__device__ inline unsigned pkh(float a, float b){
  hf2 h = __builtin_amdgcn_cvt_pkrtz(a, b);
  unsigned u; __builtin_memcpy(&u, &h, 4); return u;
}
__device__ inline hf2 u2v(unsigned u){
  hf2 h; __builtin_memcpy(&h, &u, 4); return h;
}

// ================= K1: H = feat @ W^T + Wb  [4096 x 300], K=768, MFMA ==============
__global__ __launch_bounds__(256) void k1_h(const float* __restrict__ A,
                                            const float* __restrict__ W,
                                            const float* __restrict__ Wb,
                                            float* __restrict__ H){
  __shared__ short Ah[2][64*40];
  __shared__ short Al[2][64*40];
  __shared__ short Bh[2][64*40];
  __shared__ short Bl[2][64*40];
  const int fid = blockIdx.x;
  const int wl  = (fid & 7) * 40 + (fid >> 3);
  const int y = wl / 5, x = wl % 5;
  const int m0 = y * 64, c0 = x * 64;
  const int t = threadIdx.x;
  const int lane = t & 63, w = t >> 6;
  const int wr = w >> 1, wc = w & 1;
  const int srow = t >> 2, kq = (t & 3) * 8;
  const bool bok = (c0 + srow) < 300;
  const float* Arow = A + (size_t)(m0 + srow) * 768 + kq;
  const float* Wrow = W + (size_t)(c0 + srow) * 768 + kq;
  float4 ra0, ra1, rb0, rb1;
#define K1_LD(kt) { \
    ra0 = *(const float4*)(Arow + (kt)); \
    ra1 = *(const float4*)(Arow + (kt) + 4); \
    rb0 = bok ? *(const float4*)(Wrow + (kt)) : f4z(); \
    rb1 = bok ? *(const float4*)(Wrow + (kt) + 4) : f4z(); }
  K1_LD(0)
  f32x4 acc[2][2];
  #pragma unroll
  for (int i = 0; i < 2; i++)
    #pragma unroll
    for (int j = 0; j < 2; j++)
      acc[i][j] = (f32x4){0.f, 0.f, 0.f, 0.f};
  const int fr = lane & 15;
  const int fk = (lane >> 4) * 8;
  int p = 0;
  for (int tile = 0; tile < 24; ++tile){
    {
      float av[8] = {ra0.x, ra0.y, ra0.z, ra0.w, ra1.x, ra1.y, ra1.z, ra1.w};
      float bv[8] = {rb0.x, rb0.y, rb0.z, rb0.w, rb1.x, rb1.y, rb1.z, rb1.w};
      short8 vah, val_, vbh, vbl;
      #pragma unroll
      for (int i = 0; i < 8; i++){
        unsigned short hh = f2bf(av[i]);
        vah[i] = (short)hh;
        val_[i] = (short)f2bf(av[i] - bf2f(hh));
        unsigned short gh = f2bf(bv[i]);
        vbh[i] = (short)gh;
        vbl[i] = (short)f2bf(bv[i] - bf2f(gh));
      }
      const int o = srow * 40 + kq;
      *(short8*)&Ah[p][o] = vah;
      *(short8*)&Al[p][o] = val_;
      *(short8*)&Bh[p][o] = vbh;
      *(short8*)&Bl[p][o] = vbl;
    }
    __syncthreads();
    if (tile < 23) K1_LD((tile + 1) * 32)
    {
      const int a0o = (wr*32      + fr) * 40 + fk;
      const int a1o = (wr*32 + 16 + fr) * 40 + fk;
      const int b0o = (wc*32      + fr) * 40 + fk;
      const int b1o = (wc*32 + 16 + fr) * 40 + fk;
      short8 fAh[2], fAl[2], fBh[2], fBl[2];
      fAh[0] = *(short8*)&Ah[p][a0o]; fAh[1] = *(short8*)&Ah[p][a1o];
      fAl[0] = *(short8*)&Al[p][a0o]; fAl[1] = *(short8*)&Al[p][a1o];
      fBh[0] = *(short8*)&Bh[p][b0o]; fBh[1] = *(short8*)&Bh[p][b1o];
      fBl[0] = *(short8*)&Bl[p][b0o]; fBl[1] = *(short8*)&Bl[p][b1o];
      #pragma unroll
      for (int sm = 0; sm < 2; sm++)
        #pragma unroll
        for (int sn = 0; sn < 2; sn++){
          acc[sm][sn] = __builtin_amdgcn_mfma_f32_16x16x32_bf16(fAh[sm], fBh[sn], acc[sm][sn], 0, 0, 0);
          acc[sm][sn] = __builtin_amdgcn_mfma_f32_16x16x32_bf16(fAh[sm], fBl[sn], acc[sm][sn], 0, 0, 0);
          acc[sm][sn] = __builtin_amdgcn_mfma_f32_16x16x32_bf16(fAl[sm], fBh[sn], acc[sm][sn], 0, 0, 0);
        }
    }
    p ^= 1;
  }
#undef K1_LD
  const int crow = (lane >> 4) * 4;
  const int ccol = lane & 15;
  #pragma unroll
  for (int sn = 0; sn < 2; sn++){
    const int gcol = c0 + wc*32 + sn*16 + ccol;
    if (gcol < 300){
      const float bi = Wb[gcol];
      #pragma unroll
      for (int sm = 0; sm < 2; sm++){
        const int rbase = m0 + wr*32 + sm*16 + crow;
        #pragma unroll
        for (int r = 0; r < 4; r++)
          H[(size_t)(rbase + r) * 300 + gcol] = acc[sm][sn][r] + bi;
      }
    }
  }
}

// ================= K2: S = H @ Bmat^T (+a1b cols<64)  [4096 x 128], K=300, MFMA ====
__global__ __launch_bounds__(256) void k2_s(const float* __restrict__ Hm,
                                            const float* __restrict__ a1w,
                                            const float* __restrict__ a1b,
                                            float* __restrict__ S){
  __shared__ short Ah[2][64*40];
  __shared__ short Al[2][64*40];
  __shared__ short Bh[2][64*40];
  __shared__ short Bl[2][64*40];
  const int fid = blockIdx.x;
  const int wl  = (fid & 7) * 16 + (fid >> 3);
  const int y = wl >> 1, x = wl & 1;
  const int m0 = y * 64, c0 = x * 64;
  const int t = threadIdx.x;
  const int lane = t & 63, w = t >> 6;
  const int wr = w >> 1, wc = w & 1;
  const int srow = t >> 2, kq = (t & 3) * 8;
  const int brow = c0 + srow;
  const float* Arow = Hm + (size_t)(m0 + srow) * 300;
  const float* Brow = (brow < 64) ? (a1w + (size_t)brow * 600)
                                  : (a1w + (size_t)(brow - 64) * 600 + 300);
  float4 ra0, ra1, rb0, rb1;
#define K2_LD(kt) { \
    const int k = (kt) + kq; \
    ra0 = (k <= 296) ? *(const float4*)(Arow + k)     : f4z(); \
    ra1 = (k <= 292) ? *(const float4*)(Arow + k + 4) : f4z(); \
    rb0 = (k <= 296) ? *(const float4*)(Brow + k)     : f4z(); \
    rb1 = (k <= 292) ? *(const float4*)(Brow + k + 4) : f4z(); }
  K2_LD(0)
  f32x4 acc[2][2];
  #pragma unroll
  for (int i = 0; i < 2; i++)
    #pragma unroll
    for (int j = 0; j < 2; j++)
      acc[i][j] = (f32x4){0.f, 0.f, 0.f, 0.f};
  const int fr = lane & 15;
  const int fk = (lane >> 4) * 8;
  int p = 0;
  for (int tile = 0; tile < 10; ++tile){
    {
      float av[8] = {ra0.x, ra0.y, ra0.z, ra0.w, ra1.x, ra1.y, ra1.z, ra1.w};
      float bv[8] = {rb0.x, rb0.y, rb0.z, rb0.w, rb1.x, rb1.y, rb1.z, rb1.w};
      short8 vah, val_, vbh, vbl;
      #pragma unroll
      for (int i = 0; i < 8; i++){
        unsigned short hh = f2bf(av[i]);
        vah[i] = (short)hh;
        val_[i] = (short)f2bf(av[i] - bf2f(hh));
        unsigned short gh = f2bf(bv[i]);
        vbh[i] = (short)gh;
        vbl[i] = (short)f2bf(bv[i] - bf2f(gh));
      }
      const int o = srow * 40 + kq;
      *(short8*)&Ah[p][o] = vah;
      *(short8*)&Al[p][o] = val_;
      *(short8*)&Bh[p][o] = vbh;
      *(short8*)&Bl[p][o] = vbl;
    }
    __syncthreads();
    if (tile < 9) K2_LD((tile + 1) * 32)
    {
      const int a0o = (wr*32      + fr) * 40 + fk;
      const int a1o = (wr*32 + 16 + fr) * 40 + fk;
      const int b0o = (wc*32      + fr) * 40 + fk;
      const int b1o = (wc*32 + 16 + fr) * 40 + fk;
      short8 fAh[2], fAl[2], fBh[2], fBl[2];
      fAh[0] = *(short8*)&Ah[p][a0o]; fAh[1] = *(short8*)&Ah[p][a1o];
      fAl[0] = *(short8*)&Al[p][a0o]; fAl[1] = *(short8*)&Al[p][a1o];
      fBh[0] = *(short8*)&Bh[p][b0o]; fBh[1] = *(short8*)&Bh[p][b1o];
      fBl[0] = *(short8*)&Bl[p][b0o]; fBl[1] = *(short8*)&Bl[p][b1o];
      #pragma unroll
      for (int sm = 0; sm < 2; sm++)
        #pragma unroll
        for (int sn = 0; sn < 2; sn++){
          acc[sm][sn] = __builtin_amdgcn_mfma_f32_16x16x32_bf16(fAh[sm], fBh[sn], acc[sm][sn], 0, 0, 0);
          acc[sm][sn] = __builtin_amdgcn_mfma_f32_16x16x32_bf16(fAh[sm], fBl[sn], acc[sm][sn], 0, 0, 0);
          acc[sm][sn] = __builtin_amdgcn_mfma_f32_16x16x32_bf16(fAl[sm], fBh[sn], acc[sm][sn], 0, 0, 0);
        }
    }
    p ^= 1;
  }
#undef K2_LD
  const int crow = (lane >> 4) * 4;
  const int ccol = lane & 15;
  #pragma unroll
  for (int sn = 0; sn < 2; sn++){
    const int gcol = c0 + wc*32 + sn*16 + ccol;
    const float bi = (gcol < 64) ? a1b[gcol] : 0.f;
    #pragma unroll
    for (int sm = 0; sm < 2; sm++){
      const int rbase = m0 + wr*32 + sm*16 + crow;
      #pragma unroll
      for (int r = 0; r < 4; r++)
        S[(size_t)(rbase + r) * 128 + gcol] = acc[sm][sn][r] + bi;
    }
  }
}

// ================= K3: logits + mask + per-block (max, sum-exp); packed fp16 ========
__global__ __launch_bounds__(256) void k3_logits(const float* __restrict__ S,
                                                 const float* __restrict__ adj,
                                                 const float* __restrict__ a2w,
                                                 const float* __restrict__ a2b,
                                                 float* __restrict__ L,
                                                 float* __restrict__ bm,
                                                 float* __restrict__ bs){
  __shared__ unsigned sj_u[64*33];
  __shared__ unsigned w_u[32];
  __shared__ float redm[4];
  __shared__ float reds[4];
  __shared__ float smax;
  const int b  = blockIdx.z;
  const int i0 = blockIdx.y * 32;
  const int j0 = blockIdx.x * 64;
  const int t  = threadIdx.x;
  const int j = t & 63, iq = t >> 6;
  if (t < 16){
    const float4 wv = *(const float4*)&a2w[t*4];
    w_u[t*2]     = pkh(wv.x, wv.y);
    w_u[t*2 + 1] = pkh(wv.z, wv.w);
  }
  #pragma unroll
  for (int q = 0; q < 4; q++){
    const int c = t + q*256;           // 0..1023
    const int r = c >> 4, f4i = c & 15;
    const float4 v = *(const float4*)&S[(size_t)(b*512 + j0 + r)*128 + 64 + f4i*4];
    sj_u[r*33 + f4i*2]     = pkh(v.x, v.y);
    sj_u[r*33 + f4i*2 + 1] = pkh(v.z, v.w);
  }
  // distributed si (packed): lane kk2 (0..31) holds si[row][2kk2..2kk2+1]; dup on 32..63
  const int kk2 = j & 31;
  int vsi[8];
  #pragma unroll
  for (int r = 0; r < 8; r++){
    const float2 f2 = *(const float2*)&S[(size_t)(b*512 + i0 + r*4 + iq) * 128 + 2*kk2];
    vsi[r] = (int)pkh(f2.x, f2.y);
  }
  __syncthreads();
  const float a2bv = a2b[0];
  const hf2 zero2 = __builtin_amdgcn_cvt_pkrtz(0.f, 0.f);
  float accA[8];
  #pragma unroll
  for (int r = 0; r < 8; r++) accA[r] = 0.f;
  #pragma unroll
  for (int k2 = 0; k2 < 32; k2++){
    const hf2 sj2 = u2v(sj_u[j*33 + k2]);
    const hf2 w2  = u2v(w_u[k2]);
    #pragma unroll
    for (int r = 0; r < 8; r++){
      const hf2 s2 = u2v((unsigned)__builtin_amdgcn_readlane(vsi[r], k2));
      const hf2 rl = __builtin_elementwise_max(s2 + sj2, zero2);
      accA[r] = __builtin_amdgcn_fdot2(rl, w2, accA[r], false);
    }
  }
  float l_arr[8];
  float locmax = -3e38f;
  #pragma unroll
  for (int r = 0; r < 8; r++){
    const int i = r*4 + iq;
    float e = accA[r] + a2bv;
    e = (e >= 0.f) ? e : 0.01f * e;
    size_t idxg = (size_t)(b*512 + i0 + i)*512 + j0 + j;
    float l = (adj[idxg] != 0.f) ? e : NEGINF;
    l_arr[r] = l;
    L[idxg] = l;
    locmax = fmaxf(locmax, l);
  }
  float m = waveRedMax(locmax);
  if ((t & 63) == 0) redm[t >> 6] = m;
  __syncthreads();
  if (t == 0) smax = fmaxf(fmaxf(redm[0], redm[1]), fmaxf(redm[2], redm[3]));
  __syncthreads();
  const float mb = smax;
  float sacc = 0.f;
  #pragma unroll
  for (int r = 0; r < 8; r++) sacc += __expf(l_arr[r] - mb);
  sacc = waveRedSum(sacc);
  if ((t & 63) == 0) reds[t >> 6] = sacc;
  __syncthreads();
  if (t == 0){
    const int bid = (blockIdx.z * 16 + blockIdx.y) * 8 + blockIdx.x;
    bm[bid] = mb;
    bs[bid] = (reds[0] + reds[1]) + (reds[2] + reds[3]);
  }
}

// ================= K7: out = (exp(L-mx) @ H) * inv(sum); in-block k6 reduction ======
__global__ __launch_bounds__(256) void k7_out(const float* __restrict__ Lr,
                                              const float* __restrict__ Hm,
                                              const float* __restrict__ bm,
                                              const float* __restrict__ bs,
                                              float* __restrict__ out){
  __shared__ short Ah[2][64*40];
  __shared__ short Al[2][64*40];
  __shared__ short Bh[2][64*40];
  __shared__ short Bl[2][64*40];
  __shared__ float rmx[4], rsm[4];
  const int fid = blockIdx.x;
  const int b = fid & 7, idx = fid >> 3;
  const int y = idx / 5, x = idx % 5;
  const int m0 = y * 64, c0 = x * 64;
  const int t = threadIdx.x;
  const int lane = t & 63, wv = t >> 6;
  const int wr = wv >> 1, wc = wv & 1;
  const float mload = (t < 128) ? bm[b*128 + t] : -3e38f;
  float mm = waveRedMax(mload);
  if (lane == 0) rmx[wv] = mm;
  __syncthreads();
  const float mx = fmaxf(fmaxf(rmx[0], rmx[1]), fmaxf(rmx[2], rmx[3]));
  float sload = (t < 128) ? bs[b*128 + t] * __expf(mload - mx) : 0.f;
  float ss = waveRedSum(sload);
  if (lane == 0) rsm[wv] = ss;
  __syncthreads();
  const float invs = 1.0f / ((rsm[0] + rsm[1]) + (rsm[2] + rsm[3]));
  const int srow = t >> 2, kq = (t & 3) * 8;
  const float* Lrow = Lr + (size_t)(b*512 + m0 + srow) * 512 + kq;
  const int tk = t >> 4, tn = t & 15;
  const int k0 = tk * 2, n0 = tn * 4;
  const int gcolB = c0 + n0;
  const bool bok = gcolB < 300;
  float4 ra0, ra1, hb0, hb1;
#define K7_LD(kt) { \
    ra0 = *(const float4*)(Lrow + (kt)); \
    ra1 = *(const float4*)(Lrow + (kt) + 4); \
    const float* hr = Hm + (size_t)(b*512 + (kt) + k0) * 300 + gcolB; \
    hb0 = bok ? *(const float4*)hr : f4z(); \
    hb1 = bok ? *(const float4*)(hr + 300) : f4z(); }
  K7_LD(0)
  f32x4 acc[2][2];
  #pragma unroll
  for (int i = 0; i < 2; i++)
    #pragma unroll
    for (int jj = 0; jj < 2; jj++)
      acc[i][jj] = (f32x4){0.f, 0.f, 0.f, 0.f};
  const int fr = lane & 15;
  const int fg = lane >> 4;
  const int fk = fg * 8;
  int p = 0;
  for (int tile = 0; tile < 16; ++tile){
    {
      float av[8] = {ra0.x, ra0.y, ra0.z, ra0.w, ra1.x, ra1.y, ra1.z, ra1.w};
      short8 vah, val_;
      #pragma unroll
      for (int i = 0; i < 8; i++){
        const float e = __expf(av[i] - mx);
        unsigned short hh = f2bf(e);
        vah[i] = (short)hh;
        val_[i] = (short)f2bf(e - bf2f(hh));
      }
      const int o = srow * 40 + kq;
      *(short8*)&Ah[p][o] = vah;
      *(short8*)&Al[p][o] = val_;
      #pragma unroll
      for (int i = 0; i < 4; i++){
        const float v0 = F4C(hb0, i), v1 = F4C(hb1, i);
        const unsigned short h0 = f2bf(v0), h1 = f2bf(v1);
        const unsigned short l0 = f2bf(v0 - bf2f(h0)), l1 = f2bf(v1 - bf2f(h1));
        const int n = n0 + i;
        const int kbs = (k0 >> 3) ^ (n & 3);
        const int soff = n*40 + kbs*8 + (k0 & 7);
        *(unsigned*)&Bh[p][soff] = (unsigned)h0 | ((unsigned)h1 << 16);
        *(unsigned*)&Bl[p][soff] = (unsigned)l0 | ((unsigned)l1 << 16);
      }
    }
    __syncthreads();
    if (tile < 15) K7_LD((tile + 1) * 32)
    {
      const int a0o = (wr*32      + fr) * 40 + fk;
      const int a1o = (wr*32 + 16 + fr) * 40 + fk;
      const int nb0 = wc*32      + fr;
      const int nb1 = wc*32 + 16 + fr;
      const int b0o = nb0*40 + (fg ^ (nb0 & 3)) * 8;
      const int b1o = nb1*40 + (fg ^ (nb1 & 3)) * 8;
      short8 fAh[2], fAl[2], fBh[2], fBl[2];
      fAh[0] = *(short8*)&Ah[p][a0o]; fAh[1] = *(short8*)&Ah[p][a1o];
      fAl[0] = *(short8*)&Al[p][a0o]; fAl[1] = *(short8*)&Al[p][a1o];
      fBh[0] = *(short8*)&Bh[p][b0o]; fBh[1] = *(short8*)&Bh[p][b1o];
      fBl[0] = *(short8*)&Bl[p][b0o]; fBl[1] = *(short8*)&Bl[p][b1o];
      #pragma unroll
      for (int sm = 0; sm < 2; sm++)
        #pragma unroll
        for (int sn = 0; sn < 2; sn++){
          acc[sm][sn] = __builtin_amdgcn_mfma_f32_16x16x32_bf16(fAh[sm], fBh[sn], acc[sm][sn], 0, 0, 0);
          acc[sm][sn] = __builtin_amdgcn_mfma_f32_16x16x32_bf16(fAh[sm], fBl[sn], acc[sm][sn], 0, 0, 0);
          acc[sm][sn] = __builtin_amdgcn_mfma_f32_16x16x32_bf16(fAl[sm], fBh[sn], acc[sm][sn], 0, 0, 0);
        }
    }
    p ^= 1;
  }
#undef K7_LD
  const int crow = (lane >> 4) * 4;
  const int ccol = lane & 15;
  #pragma unroll
  for (int sn = 0; sn < 2; sn++){
    const int gcol = c0 + wc*32 + sn*16 + ccol;
    if (gcol < 300){
      #pragma unroll
      for (int sm = 0; sm < 2; sm++){
        const int rbase = m0 + wr*32 + sm*16 + crow;
        #pragma unroll
        for (int r = 0; r < 4; r++)
          out[(size_t)(b*512 + rbase + r) * 300 + gcol] = acc[sm][sn][r] * invs;
      }
    }
  }
}

extern "C" void kernel_launch(void* const* d_in, const int* in_sizes, int n_in,
                              void* d_out, int out_size, void* d_ws, size_t ws_size,
                              hipStream_t stream){
  const float* adj  = (const float*)d_in[0];
  const float* feat = (const float*)d_in[1];
  const float* Ww   = (const float*)d_in[2];
  const float* Wb   = (const float*)d_in[3];
  const float* a1w  = (const float*)d_in[4];
  const float* a1b  = (const float*)d_in[5];
  const float* a2w  = (const float*)d_in[6];
  const float* a2b  = (const float*)d_in[7];
  float* out = (float*)d_out;
  char* ws = (char*)d_ws;

  float* H    = (float*)(ws + 0);           // 4,915,200 B
  float* S    = (float*)(ws + 4915200);     // 2,097,152 B
  float* L    = (float*)(ws + 7012352);     // 8,388,608 B
  float* bm   = (float*)(ws + 15400960);    // 4,096 B
  float* bs   = (float*)(ws + 15405056);    // 4,096 B

  k1_h     <<<dim3(320),      dim3(256), 0, stream>>>(feat, Ww, Wb, H);
  k2_s     <<<dim3(128),      dim3(256), 0, stream>>>(H, a1w, a1b, S);
  k3_logits<<<dim3(8, 16, 8), dim3(256), 0, stream>>>(S, adj, a2w, a2b, L, bm, bs);
  k7_out   <<<dim3(320),      dim3(256), 0, stream>>>(L, H, bm, bs, out);
}